// Round 1
// 6322.614 us; speedup vs baseline: 1.0523x; 1.0523x over previous
//
#include <hip/hip_runtime.h>

// 2-layer LSTM (B=64, T=2048, H=256), persistent kernel, SINGLE-XCD edition.
// R6 = R5 with the synchronization path converted from RMW-polling to
// L1-bypassing LOAD-polling:
//  - consumer flag poll: __hip_atomic_load(AGENT) (global_load_dword sc0,
//    L2-served, no TCC RMW serialization) -- same proven pattern as the
//    `winner` election spin in R5. The R5 RMW storm (1024 concurrent
//    global_atomic_or to 32 flag lines per phase) serialized at the TCC and
//    queued the producers' flag stores behind it.
//  - A-fragments: global_load_dwordx4 ... sc0 inline asm (L1 bypass), so the
//    per-phase whole-L1 `buffer_inv` is GONE; y/Wfc/bfc stay L1-resident.
//    Rule-18 fence: s_waitcnt vmcnt(0) + sched_barrier(0) before MFMA use.
//  - FC h1 read: 8-byte agent atomic load (last plain-load reader of a
//    device-written line; must bypass L1 once buffer_inv is removed).
//  - sliding x-window: 1 y load/phase instead of 4.
// Everything else (election, flag protocol, parities, epilogue, FC) as R5.
// Coherence argument: all device-written lines (h0buf/h1buf/flags/cnt/winner)
// are read ONLY via sc0/atomic paths; vector L1 is write-through so all
// stores reach the XCD-local L2; single-XCD election makes that L2 the
// common coherency point; vmcnt(0)-before-flag orders publish vs stamp.

#define NWG 32
#define BB 64
#define TT 2048
#define HH 256
#define HS 8    // hidden dims per WG per layer
#define RS 32   // gate rows per WG per layer (4*HS)

// workspace layout (dwords)
#define WS_H0    0        // 16384 dwords (65536 B)
#define WS_H1    16384    // 16384 dwords
#define WS_FLAGS 32768    // 32 flags, stride 16 dwords (512 dwords)
#define WS_CNT   33280    // 16 dwords
#define WS_WIN   33296    // 1 dword
#define WS_NZERO 33296    // zeroed [0, WS_NZERO); winner set separately

typedef float  f32x4  __attribute__((ext_vector_type(4)));
typedef __bf16 bf16x8 __attribute__((ext_vector_type(8)));
typedef unsigned long long u64;
typedef unsigned int u32;

__device__ __forceinline__ float sigf(float x)   { return 1.0f / (1.0f + __expf(-x)); }
__device__ __forceinline__ float tanh_f(float x) { return 2.0f / (1.0f + __expf(-2.0f * x)) - 1.0f; }

__global__ void init_ws(u32* ws) {
  int i = blockIdx.x * blockDim.x + threadIdx.x;
  for (; i < WS_NZERO; i += gridDim.x * blockDim.x) ws[i] = 0u;
  if (blockIdx.x == 0 && threadIdx.x == 0) ((int*)ws)[WS_WIN] = -1;
}

__global__ __launch_bounds__(256, 1) void lstm2_persistent(
    const float* __restrict__ y,
    const float* __restrict__ Wih0, const float* __restrict__ Whh0,
    const float* __restrict__ bih0, const float* __restrict__ bhh0,
    const float* __restrict__ Wih1, const float* __restrict__ Whh1,
    const float* __restrict__ bih1, const float* __restrict__ bhh1,
    const float* __restrict__ Wfc,  const float* __restrict__ bfc,
    float* __restrict__ out,
    u32* __restrict__ ws)
{
  __bf16* h0buf = (__bf16*)(ws + WS_H0);   // [2][NWG][BB][HS]
  __bf16* h1buf = (__bf16*)(ws + WS_H1);   // [2][NWG][BB][HS]
  int*    flags = (int*)(ws + WS_FLAGS);   // stride 16 dwords per WG
  int*    cnt   = (int*)(ws + WS_CNT);
  int*    winner= (int*)(ws + WS_WIN);

  const int tid  = threadIdx.x;

  // ---- same-XCD election: 32 WGs on one XCD participate, rest exit ----
  __shared__ int s_w;
  if (tid == 0) {
    // HW_REG_XCC_ID = 20, offset 0, size 32 -> imm = 20 | (31<<11)
    int xcc = __builtin_amdgcn_s_getreg(20 | (31 << 11)) & 0xF;
    int r = atomicAdd(&cnt[xcc], 1);               // device-scope (IC), one-time
    if (r == NWG - 1) atomicCAS(winner, -1, xcc);  // 32nd registrant claims
    int wv;
    while ((wv = __hip_atomic_load(winner, __ATOMIC_RELAXED,
                                   __HIP_MEMORY_SCOPE_AGENT)) == -1) {}
    s_w = (wv == xcc && r < NWG) ? r : -1;
  }
  __syncthreads();
  const int w = s_w;
  if (w < 0) return;   // non-participant WG exits, frees its CU

  const int wave = tid >> 6;
  const int lane = tid & 63;
  const int ml   = lane & 15;   // row-within-tile for A, col (gate row) for B
  const int kq   = lane >> 4;   // k-quad

  __shared__ float lds_g0[RS][BB + 4];
  __shared__ float lds_g1[RS][BB + 4];
  __shared__ float s_wih0[RS][4];
  __shared__ float s_b0[RS];
  __shared__ float s_b1[RS];

  // ---- load recurrent weights into per-wave VGPR B-fragments (bf16) ----
  bf16x8 w0[2][8];    // layer0: [ntile][kstep], K=256
  bf16x8 w1[2][16];   // layer1: K=512 = [Wih1 | Whh1]
  {
    #pragma unroll
    for (int n = 0; n < 2; n++) {
      const int r     = n * 16 + ml;
      const int d     = w * HS + (r & 7);
      const int rglob = (r >> 3) * 256 + d;
      #pragma unroll
      for (int s = 0; s < 8; s++) {
        const float* src = Whh0 + rglob * HH + s * 32 + kq * 8;
        bf16x8 f;
        #pragma unroll
        for (int j = 0; j < 8; j++) f[j] = (__bf16)src[j];
        w0[n][s] = f;
      }
      #pragma unroll
      for (int s = 0; s < 16; s++) {
        const int k = s * 32 + kq * 8;
        const float* src = (k < 256) ? (Wih1 + rglob * HH + k)
                                     : (Whh1 + rglob * HH + (k - 256));
        bf16x8 f;
        #pragma unroll
        for (int j = 0; j < 8; j++) f[j] = (__bf16)src[j];
        w1[n][s] = f;
      }
    }
  }

  // ---- epilogue tables in LDS ----
  if (tid < RS) {
    const int r     = tid;
    const int d     = w * HS + (r & 7);
    const int rglob = (r >> 3) * 256 + d;
    s_b0[r] = bih0[rglob] + bhh0[rglob];
    s_b1[r] = bih1[rglob] + bhh1[rglob];
    #pragma unroll
    for (int j = 0; j < 4; j++) s_wih0[r][j] = Wih0[rglob * 4 + j];
  }
  __syncthreads();

  float c0[2] = {0.f, 0.f};
  float c1[2] = {0.f, 0.f};

  const int b_epi = tid >> 2;          // epilogue batch (2 dims per thread)
  const int dl    = (tid & 3) * 2;     // first of 2 hidden dims

  // sliding 4-tap input window: x[j] holds y[b_epi, p-3+j] (or -100 pad)
  float x[4] = {-100.0f, -100.0f, -100.0f, -100.0f};

  for (int p = 0; p < TT + 2; p++) {
    const int par  = p & 1;       // parity written by L0 this phase
    const int parm = par ^ 1;     // parity of h0(p-1) / h1(p-1)

    const bool doL0 = (p < TT);
    const bool doL1 = (p >= 1 && p <= TT);

    // ---- A-fragments: h0(p-1) and h1(p-2), L1-bypassing sc0 loads ----
    // frag s, lane(ml,kq): k = s*32+kq*8 -> strip wg = s*4+kq, row = wave*16+ml
    bf16x8 a0[8], a1[8];
    {
      const int row = wave * 16 + ml;
      const __bf16* h0p = h0buf + (parm * NWG * BB + kq * BB + row) * HS;
      const __bf16* h1p = h1buf + (par  * NWG * BB + kq * BB + row) * HS;
      #pragma unroll
      for (int s = 0; s < 8; s++)
        asm volatile("global_load_dwordx4 %0, %1, off sc0"
                     : "=v"(a0[s]) : "v"(h0p + s * 4 * BB * HS) : "memory");
      #pragma unroll
      for (int s = 0; s < 8; s++)
        asm volatile("global_load_dwordx4 %0, %1, off sc0"
                     : "=v"(a1[s]) : "v"(h1p + s * 4 * BB * HS) : "memory");
    }

    // ---- slide the input window (overlaps the sc0 load latency) ----
    x[0] = x[1]; x[1] = x[2]; x[2] = x[3];
    x[3] = (p < TT) ? y[b_epi * TT + p] : -100.0f;

    // drain the sc0 loads; fence so MFMAs can't hoist above the wait (rule 18)
    asm volatile("s_waitcnt vmcnt(0)" ::: "memory");
    __builtin_amdgcn_sched_barrier(0);

    f32x4 acc00 = {0.f,0.f,0.f,0.f}, acc01 = {0.f,0.f,0.f,0.f};
    f32x4 acc10 = {0.f,0.f,0.f,0.f}, acc11 = {0.f,0.f,0.f,0.f};

    if (doL0) {
      #pragma unroll
      for (int s = 0; s < 8; s++) {
        acc00 = __builtin_amdgcn_mfma_f32_16x16x32_bf16(a0[s], w0[0][s], acc00, 0, 0, 0);
        acc01 = __builtin_amdgcn_mfma_f32_16x16x32_bf16(a0[s], w0[1][s], acc01, 0, 0, 0);
      }
    }
    if (doL1) {
      #pragma unroll
      for (int s = 0; s < 8; s++) {
        acc10 = __builtin_amdgcn_mfma_f32_16x16x32_bf16(a0[s], w1[0][s], acc10, 0, 0, 0);
        acc11 = __builtin_amdgcn_mfma_f32_16x16x32_bf16(a0[s], w1[1][s], acc11, 0, 0, 0);
      }
      #pragma unroll
      for (int s = 0; s < 8; s++) {
        acc10 = __builtin_amdgcn_mfma_f32_16x16x32_bf16(a1[s], w1[0][s + 8], acc10, 0, 0, 0);
        acc11 = __builtin_amdgcn_mfma_f32_16x16x32_bf16(a1[s], w1[1][s + 8], acc11, 0, 0, 0);
      }
    }

    // ---- spill gates to LDS (C layout: row=batch=kq*4+j, col=gate-row=ml) ----
    {
      const int bb = wave * 16 + kq * 4;
      if (doL0) {
        #pragma unroll
        for (int j = 0; j < 4; j++) lds_g0[ml     ][bb + j] = acc00[j];
        #pragma unroll
        for (int j = 0; j < 4; j++) lds_g0[16 + ml][bb + j] = acc01[j];
      }
      if (doL1) {
        #pragma unroll
        for (int j = 0; j < 4; j++) lds_g1[ml     ][bb + j] = acc10[j];
        #pragma unroll
        for (int j = 0; j < 4; j++) lds_g1[16 + ml][bb + j] = acc11[j];
      }
    }
    __syncthreads();

    // ---- L0 epilogue: gates -> (c0,h0), publish h0(p) (coalesced strip) ----
    if (doL0) {
      float hn[2];
      #pragma unroll
      for (int e = 0; e < 2; e++) {
        const int d = dl + e;
        const float gi = lds_g0[d     ][b_epi] + s_b0[d     ]
          + s_wih0[d     ][0]*x[0] + s_wih0[d     ][1]*x[1] + s_wih0[d     ][2]*x[2] + s_wih0[d     ][3]*x[3];
        const float gf = lds_g0[8 + d ][b_epi] + s_b0[8 + d ]
          + s_wih0[8 + d ][0]*x[0] + s_wih0[8 + d ][1]*x[1] + s_wih0[8 + d ][2]*x[2] + s_wih0[8 + d ][3]*x[3];
        const float gg = lds_g0[16 + d][b_epi] + s_b0[16 + d]
          + s_wih0[16 + d][0]*x[0] + s_wih0[16 + d][1]*x[1] + s_wih0[16 + d][2]*x[2] + s_wih0[16 + d][3]*x[3];
        const float go = lds_g0[24 + d][b_epi] + s_b0[24 + d]
          + s_wih0[24 + d][0]*x[0] + s_wih0[24 + d][1]*x[1] + s_wih0[24 + d][2]*x[2] + s_wih0[24 + d][3]*x[3];
        const float cn = sigf(gf) * c0[e] + sigf(gi) * tanh_f(gg);
        c0[e] = cn;
        hn[e] = sigf(go) * tanh_f(cn);
      }
      union { __bf16 h[2]; u32 u; } pk;
      pk.h[0] = (__bf16)hn[0]; pk.h[1] = (__bf16)hn[1];
      *(u32*)(h0buf + (par * NWG * BB + w * BB + b_epi) * HS + dl) = pk.u;
    }

    // ---- L1 epilogue: publish h1(p-1) (coalesced strip) ----
    if (doL1) {
      float hn[2];
      #pragma unroll
      for (int e = 0; e < 2; e++) {
        const int d = dl + e;
        const float gi = lds_g1[d     ][b_epi] + s_b1[d     ];
        const float gf = lds_g1[8 + d ][b_epi] + s_b1[8 + d ];
        const float gg = lds_g1[16 + d][b_epi] + s_b1[16 + d];
        const float go = lds_g1[24 + d][b_epi] + s_b1[24 + d];
        const float cn = sigf(gf) * c1[e] + sigf(gi) * tanh_f(gg);
        c1[e] = cn;
        hn[e] = sigf(go) * tanh_f(cn);
      }
      union { __bf16 h[2]; u32 u; } pk;
      pk.h[0] = (__bf16)hn[0]; pk.h[1] = (__bf16)hn[1];
      *(u32*)(h1buf + (parm * NWG * BB + w * BB + b_epi) * HS + dl) = pk.u;
    }

    // ---- barrier publish: drain h stores to L2, then stamp flag ----
    asm volatile("s_waitcnt vmcnt(0)" ::: "memory");
    __syncthreads();
    if (tid == 0)
      __hip_atomic_store(&flags[w * 16], p + 2, __ATOMIC_RELAXED,
                         __HIP_MEMORY_SCOPE_WORKGROUP);   // plain store -> local L2

    // ---- FC output for step p-2 (overlaps flag propagation) ----
    if (p >= 2) {
      const int t = p - 2;
      const int b = 2 * w + (wave & 1);
      const int c = wave >> 1;
      const __bf16* h1r = h1buf + (par * NWG * BB + (lane >> 1) * BB + b) * HS + (lane & 1) * 4;
      union { u64 u; __bf16 h[4]; } c4;
      c4.u = __hip_atomic_load((u64*)h1r, __ATOMIC_RELAXED,
                               __HIP_MEMORY_SCOPE_AGENT);   // L1-bypass read
      float s = 0.f;
      #pragma unroll
      for (int j = 0; j < 4; j++)
        s += (float)c4.h[j] * Wfc[c * HH + lane * 4 + j];
      #pragma unroll
      for (int off = 32; off > 0; off >>= 1) s += __shfl_down(s, off, 64);
      if (lane == 0) out[b * (TT * 2) + t * 2 + c] = s + bfc[c];
    }

    // ---- barrier wait: agent-scope LOAD poll (L2-served, no RMW storm) ----
    if (tid < NWG) {
      while (__hip_atomic_load(&flags[tid * 16], __ATOMIC_RELAXED,
                               __HIP_MEMORY_SCOPE_AGENT) < p + 2) {}
    }
    __syncthreads();
  }
}

extern "C" void kernel_launch(void* const* d_in, const int* in_sizes, int n_in,
                              void* d_out, int out_size, void* d_ws, size_t ws_size,
                              hipStream_t stream) {
  u32* ws = (u32*)d_ws;
  init_ws<<<dim3(64), dim3(256), 0, stream>>>(ws);
  lstm2_persistent<<<dim3(256), dim3(256), 0, stream>>>(
      (const float*)d_in[0],  (const float*)d_in[1], (const float*)d_in[2],
      (const float*)d_in[3],  (const float*)d_in[4], (const float*)d_in[5],
      (const float*)d_in[6],  (const float*)d_in[7], (const float*)d_in[8],
      (const float*)d_in[9],  (const float*)d_in[10],
      (float*)d_out, ws);
}

// Round 2
// 5927.419 us; speedup vs baseline: 1.1225x; 1.0667x over previous
//
#include <hip/hip_runtime.h>

// 2-layer LSTM (B=64, T=2048, H=256), persistent kernel, SINGLE-XCD edition.
// R7 = R6 with DOUBLED OCCUPANCY: 64 participant WGs (2 per CU -> 2 waves/SIMD)
// instead of 32 (1 wave/SIMD). R6's counters showed OccupancyPercent=1.5
// (exactly 1 wave/SIMD on the 32 active CUs): every L2 load, MFMA chain,
// transcendental and poll latency was fully exposed serially. Halving the
// per-WG work (16 gate rows = 4 hidden dims per layer per WG) lets two WGs
// per CU overlap each other's stalls.
//  - global h layout UNCHANGED: [parity][32 strips][64 batch][8 dims] bf16;
//    WG w owns dims [w*4, w*4+4) = half of strip w>>1.
//  - L1 accumulator split into two independent 8-chains (k-halves) for ILP
//    (single n-tile would otherwise be one 16-deep dependent MFMA chain).
//  - 64 flags; poll = wave 0's 64 lanes, agent-scope relaxed loads (R6 path).
//  - grid 768 so some XCD is guaranteed >= 64 registrants (pigeonhole).
// Coherence protocol byte-identical to R6: sc0 loads for A-frags, plain
// write-through stores for h, vmcnt(0) drain before flag stamp, agent-scope
// load polling, single-XCD L2 as the coherency point.

#define NWG 64      // participant workgroups
#define NSTRIP 32   // h strips (8 dims each) -- global h layout unchanged
#define BB 64
#define TT 2048
#define HH 256
#define HS 8        // dims per strip
#define HSW 4       // hidden dims per WG per layer
#define RS 16       // gate rows per WG per layer (4*HSW)

// workspace layout (dwords)
#define WS_H0    0        // 16384 dwords (65536 B)
#define WS_H1    16384    // 16384 dwords
#define WS_FLAGS 32768    // 64 flags, stride 16 dwords (1024 dwords)
#define WS_CNT   33792    // 16 dwords
#define WS_WIN   33808    // 1 dword
#define WS_NZERO 33808    // zeroed [0, WS_NZERO); winner set separately

typedef float  f32x4  __attribute__((ext_vector_type(4)));
typedef __bf16 bf16x8 __attribute__((ext_vector_type(8)));
typedef unsigned long long u64;
typedef unsigned int u32;

__device__ __forceinline__ float sigf(float x)   { return 1.0f / (1.0f + __expf(-x)); }
__device__ __forceinline__ float tanh_f(float x) { return 2.0f / (1.0f + __expf(-2.0f * x)) - 1.0f; }

__global__ void init_ws(u32* ws) {
  int i = blockIdx.x * blockDim.x + threadIdx.x;
  for (; i < WS_NZERO; i += gridDim.x * blockDim.x) ws[i] = 0u;
  if (blockIdx.x == 0 && threadIdx.x == 0) ((int*)ws)[WS_WIN] = -1;
}

__global__ __launch_bounds__(256, 2) void lstm2_persistent(
    const float* __restrict__ y,
    const float* __restrict__ Wih0, const float* __restrict__ Whh0,
    const float* __restrict__ bih0, const float* __restrict__ bhh0,
    const float* __restrict__ Wih1, const float* __restrict__ Whh1,
    const float* __restrict__ bih1, const float* __restrict__ bhh1,
    const float* __restrict__ Wfc,  const float* __restrict__ bfc,
    float* __restrict__ out,
    u32* __restrict__ ws)
{
  __bf16* h0buf = (__bf16*)(ws + WS_H0);   // [2][NSTRIP][BB][HS]
  __bf16* h1buf = (__bf16*)(ws + WS_H1);   // [2][NSTRIP][BB][HS]
  int*    flags = (int*)(ws + WS_FLAGS);   // stride 16 dwords per WG
  int*    cnt   = (int*)(ws + WS_CNT);
  int*    winner= (int*)(ws + WS_WIN);

  const int tid  = threadIdx.x;

  // ---- same-XCD election: first 64 WGs on one XCD participate, rest exit ----
  __shared__ int s_w;
  if (tid == 0) {
    // HW_REG_XCC_ID = 20, offset 0, size 32 -> imm = 20 | (31<<11)
    int xcc = __builtin_amdgcn_s_getreg(20 | (31 << 11)) & 0xF;
    int r = atomicAdd(&cnt[xcc], 1);               // device-scope (IC), one-time
    if (r == NWG - 1) atomicCAS(winner, -1, xcc);  // 64th registrant claims
    int wv;
    while ((wv = __hip_atomic_load(winner, __ATOMIC_RELAXED,
                                   __HIP_MEMORY_SCOPE_AGENT)) == -1) {}
    s_w = (wv == xcc && r < NWG) ? r : -1;
  }
  __syncthreads();
  const int w = s_w;
  if (w < 0) return;   // non-participant WG exits, frees its CU

  const int wave = tid >> 6;
  const int lane = tid & 63;
  const int ml   = lane & 15;   // row-within-tile for A, gate row for B
  const int kq   = lane >> 4;   // k-quad

  __shared__ float lds_g0[RS][BB + 4];
  __shared__ float lds_g1[RS][BB + 4];
  __shared__ float s_wih0[RS][4];
  __shared__ float s_b0[RS];
  __shared__ float s_b1[RS];

  // ---- load recurrent weights into per-wave VGPR B-fragments (bf16) ----
  // local gate row r = ml (0..15): gate = r>>2, dim-in-WG = r&3
  bf16x8 w0f[8];    // layer0: K=256
  bf16x8 w1f[16];   // layer1: K=512 = [Wih1 | Whh1]
  {
    const int r     = ml;
    const int rglob = (r >> 2) * 256 + w * HSW + (r & 3);
    #pragma unroll
    for (int s = 0; s < 8; s++) {
      const float* src = Whh0 + rglob * HH + s * 32 + kq * 8;
      bf16x8 f;
      #pragma unroll
      for (int j = 0; j < 8; j++) f[j] = (__bf16)src[j];
      w0f[s] = f;
    }
    #pragma unroll
    for (int s = 0; s < 16; s++) {
      const int k = s * 32 + kq * 8;
      const float* src = (k < 256) ? (Wih1 + rglob * HH + k)
                                   : (Whh1 + rglob * HH + (k - 256));
      bf16x8 f;
      #pragma unroll
      for (int j = 0; j < 8; j++) f[j] = (__bf16)src[j];
      w1f[s] = f;
    }
  }

  // ---- epilogue tables in LDS ----
  if (tid < RS) {
    const int r     = tid;
    const int rglob = (r >> 2) * 256 + w * HSW + (r & 3);
    s_b0[r] = bih0[rglob] + bhh0[rglob];
    s_b1[r] = bih1[rglob] + bhh1[rglob];
    #pragma unroll
    for (int j = 0; j < 4; j++) s_wih0[r][j] = Wih0[rglob * 4 + j];
  }
  __syncthreads();

  float c0 = 0.f, c1 = 0.f;

  const int b_epi = tid >> 2;          // epilogue batch (1 dim per thread)
  const int dl    = tid & 3;           // hidden dim within WG

  // sliding 4-tap input window: x[j] holds y[b_epi, p-3+j] (or -100 pad)
  float x[4] = {-100.0f, -100.0f, -100.0f, -100.0f};

  for (int p = 0; p < TT + 2; p++) {
    const int par  = p & 1;       // parity written by L0 this phase
    const int parm = par ^ 1;     // parity of h0(p-1) / h1(p-1)

    const bool doL0 = (p < TT);
    const bool doL1 = (p >= 1 && p <= TT);

    // ---- A-fragments: h0(p-1) and h1(p-2), L1-bypassing sc0 loads ----
    // frag s, lane(ml,kq): k = s*32+kq*8 -> strip = s*4+kq, row = wave*16+ml
    bf16x8 a0[8], a1[8];
    {
      const int row = wave * 16 + ml;
      const __bf16* h0p = h0buf + (parm * NSTRIP * BB + kq * BB + row) * HS;
      const __bf16* h1p = h1buf + (par  * NSTRIP * BB + kq * BB + row) * HS;
      #pragma unroll
      for (int s = 0; s < 8; s++)
        asm volatile("global_load_dwordx4 %0, %1, off sc0"
                     : "=v"(a0[s]) : "v"(h0p + s * 4 * BB * HS) : "memory");
      #pragma unroll
      for (int s = 0; s < 8; s++)
        asm volatile("global_load_dwordx4 %0, %1, off sc0"
                     : "=v"(a1[s]) : "v"(h1p + s * 4 * BB * HS) : "memory");
    }

    // ---- slide the input window (overlaps the sc0 load latency) ----
    x[0] = x[1]; x[1] = x[2]; x[2] = x[3];
    x[3] = (p < TT) ? y[b_epi * TT + p] : -100.0f;

    // drain the sc0 loads; fence so MFMAs can't hoist above the wait (rule 18)
    asm volatile("s_waitcnt vmcnt(0)" ::: "memory");
    __builtin_amdgcn_sched_barrier(0);

    f32x4 acc0  = {0.f,0.f,0.f,0.f};
    f32x4 acc1a = {0.f,0.f,0.f,0.f};
    f32x4 acc1b = {0.f,0.f,0.f,0.f};

    if (doL0) {
      #pragma unroll
      for (int s = 0; s < 8; s++)
        acc0 = __builtin_amdgcn_mfma_f32_16x16x32_bf16(a0[s], w0f[s], acc0, 0, 0, 0);
    }
    if (doL1) {
      #pragma unroll
      for (int s = 0; s < 8; s++)
        acc1a = __builtin_amdgcn_mfma_f32_16x16x32_bf16(a0[s], w1f[s], acc1a, 0, 0, 0);
      #pragma unroll
      for (int s = 0; s < 8; s++)
        acc1b = __builtin_amdgcn_mfma_f32_16x16x32_bf16(a1[s], w1f[s + 8], acc1b, 0, 0, 0);
    }

    // ---- spill gates to LDS (C layout: row=batch=kq*4+j, col=gate-row=ml) ----
    {
      const int bb = wave * 16 + kq * 4;
      if (doL0) {
        #pragma unroll
        for (int j = 0; j < 4; j++) lds_g0[ml][bb + j] = acc0[j];
      }
      if (doL1) {
        #pragma unroll
        for (int j = 0; j < 4; j++) lds_g1[ml][bb + j] = acc1a[j] + acc1b[j];
      }
    }
    __syncthreads();

    // ---- L0 epilogue: gates -> (c0,h0), publish h0(p) ----
    if (doL0) {
      const float gi = lds_g0[dl     ][b_epi] + s_b0[dl     ]
        + s_wih0[dl     ][0]*x[0] + s_wih0[dl     ][1]*x[1] + s_wih0[dl     ][2]*x[2] + s_wih0[dl     ][3]*x[3];
      const float gf = lds_g0[4 + dl ][b_epi] + s_b0[4 + dl ]
        + s_wih0[4 + dl ][0]*x[0] + s_wih0[4 + dl ][1]*x[1] + s_wih0[4 + dl ][2]*x[2] + s_wih0[4 + dl ][3]*x[3];
      const float gg = lds_g0[8 + dl ][b_epi] + s_b0[8 + dl ]
        + s_wih0[8 + dl ][0]*x[0] + s_wih0[8 + dl ][1]*x[1] + s_wih0[8 + dl ][2]*x[2] + s_wih0[8 + dl ][3]*x[3];
      const float go = lds_g0[12 + dl][b_epi] + s_b0[12 + dl]
        + s_wih0[12 + dl][0]*x[0] + s_wih0[12 + dl][1]*x[1] + s_wih0[12 + dl][2]*x[2] + s_wih0[12 + dl][3]*x[3];
      const float cn = sigf(gf) * c0 + sigf(gi) * tanh_f(gg);
      c0 = cn;
      const float hn = sigf(go) * tanh_f(cn);
      h0buf[(par * NSTRIP * BB + (w >> 1) * BB + b_epi) * HS + (w & 1) * 4 + dl] = (__bf16)hn;
    }

    // ---- L1 epilogue: publish h1(p-1) ----
    if (doL1) {
      const float gi = lds_g1[dl     ][b_epi] + s_b1[dl     ];
      const float gf = lds_g1[4 + dl ][b_epi] + s_b1[4 + dl ];
      const float gg = lds_g1[8 + dl ][b_epi] + s_b1[8 + dl ];
      const float go = lds_g1[12 + dl][b_epi] + s_b1[12 + dl];
      const float cn = sigf(gf) * c1 + sigf(gi) * tanh_f(gg);
      c1 = cn;
      const float hn = sigf(go) * tanh_f(cn);
      h1buf[(parm * NSTRIP * BB + (w >> 1) * BB + b_epi) * HS + (w & 1) * 4 + dl] = (__bf16)hn;
    }

    // ---- barrier publish: drain h stores to L2, then stamp flag ----
    asm volatile("s_waitcnt vmcnt(0)" ::: "memory");
    __syncthreads();
    if (tid == 0)
      __hip_atomic_store(&flags[w * 16], p + 2, __ATOMIC_RELAXED,
                         __HIP_MEMORY_SCOPE_WORKGROUP);   // plain store -> local L2

    // ---- FC output for step p-2 (overlaps flag propagation) ----
    if (p >= 2 && wave < 2) {
      const int t = p - 2;
      const int b = w;              // batch = WG index (0..63)
      const int c = wave;           // class
      const __bf16* h1r = h1buf + (par * NSTRIP * BB + (lane >> 1) * BB + b) * HS + (lane & 1) * 4;
      union { u64 u; __bf16 h[4]; } c4;
      c4.u = __hip_atomic_load((u64*)h1r, __ATOMIC_RELAXED,
                               __HIP_MEMORY_SCOPE_AGENT);   // L1-bypass read
      float s = 0.f;
      #pragma unroll
      for (int j = 0; j < 4; j++)
        s += (float)c4.h[j] * Wfc[c * HH + lane * 4 + j];
      #pragma unroll
      for (int off = 32; off > 0; off >>= 1) s += __shfl_down(s, off, 64);
      if (lane == 0) out[b * (TT * 2) + t * 2 + c] = s + bfc[c];
    }

    // ---- barrier wait: agent-scope LOAD poll (L2-served, no RMW storm) ----
    if (tid < NWG) {
      while (__hip_atomic_load(&flags[tid * 16], __ATOMIC_RELAXED,
                               __HIP_MEMORY_SCOPE_AGENT) < p + 2) {}
    }
    __syncthreads();
  }
}

extern "C" void kernel_launch(void* const* d_in, const int* in_sizes, int n_in,
                              void* d_out, int out_size, void* d_ws, size_t ws_size,
                              hipStream_t stream) {
  u32* ws = (u32*)d_ws;
  init_ws<<<dim3(64), dim3(256), 0, stream>>>(ws);
  lstm2_persistent<<<dim3(768), dim3(256), 0, stream>>>(
      (const float*)d_in[0],  (const float*)d_in[1], (const float*)d_in[2],
      (const float*)d_in[3],  (const float*)d_in[4], (const float*)d_in[5],
      (const float*)d_in[6],  (const float*)d_in[7], (const float*)d_in[8],
      (const float*)d_in[9],  (const float*)d_in[10],
      (float*)d_out, ws);
}